// Round 1
// baseline (196.156 us; speedup 1.0000x reference)
//
#include <hip/hip_runtime.h>
#include <hip/hip_bf16.h>
#include <cstdint>

// Problem constants
#define BN 16
#define LL 3
#define NN 512
#define DD 1024
#define HH 4096
#define SS 24576    // B*N*L tokens
#define LNTOK 1536  // L*N tokens per batch
#define CAP 8192    // ceil(S/E)

// ws offsets in 4-byte words
#define OFF_IDX   0        // int[S]
#define OFF_GVAL  24576    // float[S]
#define OFF_GS    49152    // float[S]
#define OFF_HIST  73728    // int[96*3]
#define OFF_CBASE 74240    // int[96*3]
#define OFF_GSUM  74752    // float[3]
#define OFF_GBE   74816    // float[16*3]
#define OFF_CNTB  74880    // float[16]
#define OFF_Z     75776    // float[16*3*1024]
#define OFF_YS    124928   // float[16*1024]
#define OFF_END   141312

// K1: gating. grid 384 x 256. Each block: 64 tokens; each wave: 16 tokens.
__global__ __launch_bounds__(256) void k1_gating(const float* __restrict__ x,
                                                 const float* __restrict__ wg,
                                                 int* __restrict__ idx,
                                                 float* __restrict__ gval,
                                                 int* __restrict__ hist,
                                                 float* __restrict__ gsum) {
  __shared__ float wgT[3][1024];
  __shared__ float sG[3];
  __shared__ int sH[3];
  int tid = threadIdx.x;
  for (int i = tid; i < 3072; i += 256) wgT[i % 3][i / 3] = wg[i];
  if (tid < 3) { sG[tid] = 0.f; sH[tid] = 0; }
  __syncthreads();
  int lane = tid & 63, w = tid >> 6;
  float lg0 = 0, lg1 = 0, lg2 = 0;
  int lh0 = 0, lh1 = 0, lh2 = 0;
  int tbase = blockIdx.x * 64 + w * 16;
  for (int k = 0; k < 16; ++k) {
    int t = tbase + k;
    int b = t / LNTOK, r = t % LNTOK;
    int n = r / LL, l = r % LL;
    const float* row = x + (size_t)((b * LL + l) * NN + n) * DD;
    float d0 = 0, d1 = 0, d2 = 0;
#pragma unroll
    for (int q = 0; q < 4; ++q) {
      int dd = q * 256 + lane * 4;
      float4 v = *(const float4*)(row + dd);
      float4 w0 = *(const float4*)(&wgT[0][dd]);
      float4 w1 = *(const float4*)(&wgT[1][dd]);
      float4 w2 = *(const float4*)(&wgT[2][dd]);
      d0 += v.x * w0.x + v.y * w0.y + v.z * w0.z + v.w * w0.w;
      d1 += v.x * w1.x + v.y * w1.y + v.z * w1.z + v.w * w1.w;
      d2 += v.x * w2.x + v.y * w2.y + v.z * w2.z + v.w * w2.w;
    }
#pragma unroll
    for (int off = 32; off > 0; off >>= 1) {
      d0 += __shfl_xor(d0, off);
      d1 += __shfl_xor(d1, off);
      d2 += __shfl_xor(d2, off);
    }
    if (lane == 0) {
      float m = d0; int id = 0;
      if (d1 > m) { m = d1; id = 1; }
      if (d2 > m) { m = d2; id = 2; }
      float e0 = expf(d0 - m), e1 = expf(d1 - m), e2 = expf(d2 - m);
      float s = e0 + e1 + e2, inv = 1.0f / s;
      idx[t] = id;
      gval[t] = inv;  // softmax prob of the argmax expert: exp(0)/s
      lg0 += e0 * inv; lg1 += e1 * inv; lg2 += e2 * inv;
      if (id == 0) lh0++; else if (id == 1) lh1++; else lh2++;
    }
  }
  if (lane == 0) {
    atomicAdd(&sG[0], lg0); atomicAdd(&sG[1], lg1); atomicAdd(&sG[2], lg2);
    atomicAdd(&sH[0], lh0); atomicAdd(&sH[1], lh1); atomicAdd(&sH[2], lh2);
  }
  __syncthreads();
  if (tid < 3) {
    atomicAdd(&gsum[tid], sG[tid]);
    atomicAdd(&hist[(blockIdx.x >> 2) * 3 + tid], sH[tid]);
  }
}

// K2: chunk prefix scan + l_aux + mask count. 1 block x 256.
__global__ __launch_bounds__(256) void k2_scan(const void* __restrict__ maskp,
                                               const int* __restrict__ hist,
                                               int* __restrict__ cbase,
                                               const float* __restrict__ gsum,
                                               float* __restrict__ cntb,
                                               float* __restrict__ out_laux) {
  __shared__ int det;
  __shared__ int scnt[16];
  int tid = threadIdx.x;
  if (tid == 0) det = 0;
  if (tid < 16) scnt[tid] = 0;
  __syncthreads();
  const uint32_t* mw = (const uint32_t*)maskp;
  // sniff encoding over first LNTOK words (safe in all encodings)
  for (int i = tid; i < LNTOK; i += 256) {
    uint32_t v = mw[i];
    if (v == 0x3F800000u) det = 2;        // float32 0/1
    else if (v > 1u) det = 1;             // packed bool bytes
  }
  __syncthreads();
  int mode = det;
  if (mode == 1) {
    const uint8_t* mb = (const uint8_t*)maskp;
    for (int i = tid; i < SS; i += 256)
      if (mb[i] == 0) atomicAdd(&scnt[i / LNTOK], 1);
  } else {
    for (int i = tid; i < SS; i += 256)
      if (mw[i] == 0) atomicAdd(&scnt[i / LNTOK], 1);
  }
  __syncthreads();
  if (tid < 16) {
    int c = scnt[tid];
    cntb[tid] = (float)(c < 1 ? 1 : c);
  }
  if (tid == 0) {
    int r0 = 0, r1 = 0, r2 = 0;
    for (int c = 0; c < 96; ++c) {
      cbase[c * 3 + 0] = r0; cbase[c * 3 + 1] = r1; cbase[c * 3 + 2] = r2;
      r0 += hist[c * 3 + 0]; r1 += hist[c * 3 + 1]; r2 += hist[c * 3 + 2];
    }
    float invS = 1.0f / (float)SS;
    float laux = 3.0f * (gsum[0] * invS * ((float)r0 * invS) +
                         gsum[1] * invS * ((float)r1 * invS) +
                         gsum[2] * invS * ((float)r2 * invS));
    *out_laux = laux;
  }
}

// K3a: within-chunk arrival rank -> keep -> gate_s; also per (b,e) gate sums.
// grid 96 x 256 (one chunk of 256 tokens per block)
__global__ __launch_bounds__(256) void k3a_pos(const int* __restrict__ idx,
                                               const float* __restrict__ gval,
                                               const int* __restrict__ cbase,
                                               float* __restrict__ gs,
                                               float* __restrict__ gbe) {
  __shared__ int whist[4][3];
  __shared__ float sgbe[3];
  int tid = threadIdx.x;
  if (tid < 3) sgbe[tid] = 0.f;
  int t = blockIdx.x * 256 + tid;
  int e = idx[t];
  float gv = gval[t];
  int lane = tid & 63, w = tid >> 6;
  unsigned long long m0 = __ballot(e == 0);
  unsigned long long m1 = __ballot(e == 1);
  unsigned long long m2 = __ballot(e == 2);
  if (lane == 0) {
    whist[w][0] = __popcll(m0);
    whist[w][1] = __popcll(m1);
    whist[w][2] = __popcll(m2);
  }
  __syncthreads();
  int pre = 0;
  for (int ww = 0; ww < 3; ++ww)
    if (ww < w) pre += whist[ww][e];
  unsigned long long lt = (1ull << lane) - 1ull;
  unsigned long long me = (e == 0) ? m0 : (e == 1) ? m1 : m2;
  int within = __popcll(me & lt);
  int pos = cbase[blockIdx.x * 3 + e] + pre + within;
  float g = (pos < CAP) ? gv : 0.f;
  gs[t] = g;
  atomicAdd(&sgbe[e], g);
  __syncthreads();
  if (tid < 3) atomicAdd(&gbe[(blockIdx.x / 6) * 3 + tid], sgbe[tid]);
}

// K3b: z[b,e,:] += gate_s * x[t].  grid 384 x 256 (64 tokens per block).
__global__ __launch_bounds__(256) void k3b_zacc(const float* __restrict__ x,
                                                const int* __restrict__ idx,
                                                const float* __restrict__ gs,
                                                float* __restrict__ z) {
  __shared__ float sg[64];
  __shared__ int se[64];
  int tid = threadIdx.x;
  int t0 = blockIdx.x * 64;
  if (tid < 64) { sg[tid] = gs[t0 + tid]; se[tid] = idx[t0 + tid]; }
  __syncthreads();
  float a0[4] = {0, 0, 0, 0}, a1[4] = {0, 0, 0, 0}, a2[4] = {0, 0, 0, 0};
  int b = t0 / LNTOK;
  for (int i = 0; i < 64; ++i) {
    float g = sg[i];
    if (g == 0.f) continue;   // uniform branch (broadcast from LDS)
    int t = t0 + i;
    int r = t % LNTOK;
    int n = r / LL, l = r % LL;
    float4 v = *(const float4*)(x + (size_t)((b * LL + l) * NN + n) * DD + tid * 4);
    int e = se[i];
    if (e == 0)      { a0[0] += g * v.x; a0[1] += g * v.y; a0[2] += g * v.z; a0[3] += g * v.w; }
    else if (e == 1) { a1[0] += g * v.x; a1[1] += g * v.y; a1[2] += g * v.z; a1[3] += g * v.w; }
    else             { a2[0] += g * v.x; a2[1] += g * v.y; a2[2] += g * v.z; a2[3] += g * v.w; }
  }
  float* zb = z + (size_t)b * 3 * DD;
#pragma unroll
  for (int j = 0; j < 4; ++j) {
    atomicAdd(&zb[0 * DD + tid * 4 + j], a0[j]);
    atomicAdd(&zb[1 * DD + tid * 4 + j], a1[j]);
    atomicAdd(&zb[2 * DD + tid * 4 + j], a2[j]);
  }
}

// K4a: ysum init with bias term: ys[b,d] = sum_e gbe[b,e]*be[e,d]. grid 64 x 256.
__global__ __launch_bounds__(256) void k4a_init(const float* __restrict__ gbe,
                                                const float* __restrict__ be,
                                                float* __restrict__ ys) {
  int i = blockIdx.x * 256 + threadIdx.x;  // 16384
  int b = i >> 10, d = i & 1023;
  ys[i] = gbe[b * 3 + 0] * be[0 * DD + d] +
          gbe[b * 3 + 1] * be[1 * DD + d] +
          gbe[b * 3 + 2] * be[2 * DD + d];
}

// K4: ysum += z[16,3072] @ We[3072,1024].  grid 192 = 16 ntiles x 12 ksplits.
__global__ __launch_bounds__(256) void k4_we(const float* __restrict__ z,
                                             const float* __restrict__ We,
                                             float* __restrict__ ys) {
  __shared__ float At[16][256];
  __shared__ float Ct[16][64];
  int tid = threadIdx.x;
  int nt = blockIdx.x & 15, ks = blockIdx.x >> 4;
  int n0 = nt * 64, k0 = ks * 256;
  for (int i = tid; i < 16 * 256; i += 256) {
    int m = i >> 8, kk = i & 255;
    At[m][kk] = z[m * 3072 + k0 + kk];
  }
  for (int i = tid; i < 1024; i += 256) ((float*)Ct)[i] = 0.f;
  __syncthreads();
  int nl = tid & 63, kg = tid >> 6;
  float acc[16];
#pragma unroll
  for (int m = 0; m < 16; ++m) acc[m] = 0.f;
  for (int kk = kg * 64; kk < kg * 64 + 64; ++kk) {
    float bv = We[(size_t)(k0 + kk) * 1024 + n0 + nl];
#pragma unroll
    for (int m = 0; m < 16; ++m) acc[m] += At[m][kk] * bv;
  }
#pragma unroll
  for (int m = 0; m < 16; ++m) atomicAdd(&Ct[m][nl], acc[m]);
  __syncthreads();
  for (int i = tid; i < 1024; i += 256) {
    int m = i >> 6, h = i & 63;
    atomicAdd(&ys[m * 1024 + n0 + h], Ct[m][h]);
  }
}

// K5: out0[b,h] = (ys[b,:] @ Wp[:,h] + LNTOK*bp[h]) / cnt[b]. grid 128 x 256.
__global__ __launch_bounds__(256) void k5_out(const float* __restrict__ ys,
                                              const float* __restrict__ Wp,
                                              const float* __restrict__ bp,
                                              const float* __restrict__ cntb,
                                              float* __restrict__ out) {
  __shared__ float Ct[16][32];
  int tid = threadIdx.x;
  int n0 = blockIdx.x * 32;
  for (int i = tid; i < 512; i += 256) ((float*)Ct)[i] = 0.f;
  __syncthreads();
  int nl = tid & 31, kg = tid >> 5;  // 8 k-groups of 128
  float acc[16];
#pragma unroll
  for (int m = 0; m < 16; ++m) acc[m] = 0.f;
  for (int k = kg * 128; k < kg * 128 + 128; ++k) {
    float bv = Wp[(size_t)k * HH + n0 + nl];
#pragma unroll
    for (int m = 0; m < 16; ++m) acc[m] += ys[m * 1024 + k] * bv;
  }
#pragma unroll
  for (int m = 0; m < 16; ++m) atomicAdd(&Ct[m][nl], acc[m]);
  __syncthreads();
  for (int i = tid; i < 512; i += 256) {
    int m = i >> 5, h = i & 31;
    out[(size_t)m * HH + n0 + h] = (Ct[m][h] + (float)LNTOK * bp[n0 + h]) / cntb[m];
  }
}

extern "C" void kernel_launch(void* const* d_in, const int* in_sizes, int n_in,
                              void* d_out, int out_size, void* d_ws, size_t ws_size,
                              hipStream_t stream) {
  const float* x  = (const float*)d_in[0];
  const void*  mask = d_in[1];
  const float* wg = (const float*)d_in[2];
  const float* We = (const float*)d_in[3];
  const float* be = (const float*)d_in[4];
  const float* Wp = (const float*)d_in[5];
  const float* bp = (const float*)d_in[6];
  float* out = (float*)d_out;
  float* wsf = (float*)d_ws;
  int*   wsi = (int*)d_ws;

  // zero hist/cbase/gsum/gbe/cntb/z (ws is NOT re-poisoned between replays,
  // so we must zero our atomic targets every call)
  hipMemsetAsync((char*)d_ws + (size_t)OFF_HIST * 4, 0,
                 (size_t)(OFF_Z + 16 * 3 * 1024 - OFF_HIST) * 4, stream);

  k1_gating<<<384, 256, 0, stream>>>(x, wg, wsi + OFF_IDX, wsf + OFF_GVAL,
                                     wsi + OFF_HIST, wsf + OFF_GSUM);
  k2_scan<<<1, 256, 0, stream>>>(mask, wsi + OFF_HIST, wsi + OFF_CBASE,
                                 wsf + OFF_GSUM, wsf + OFF_CNTB, out + 65536);
  k3a_pos<<<96, 256, 0, stream>>>(wsi + OFF_IDX, wsf + OFF_GVAL,
                                  wsi + OFF_CBASE, wsf + OFF_GS, wsf + OFF_GBE);
  k3b_zacc<<<384, 256, 0, stream>>>(x, wsi + OFF_IDX, wsf + OFF_GS, wsf + OFF_Z);
  k4a_init<<<64, 256, 0, stream>>>(wsf + OFF_GBE, be, wsf + OFF_YS);
  k4_we<<<192, 256, 0, stream>>>(wsf + OFF_Z, We, wsf + OFF_YS);
  k5_out<<<128, 256, 0, stream>>>(wsf + OFF_YS, Wp, bp, wsf + OFF_CNTB, out);
}

// Round 2
// 184.331 us; speedup vs baseline: 1.0641x; 1.0641x over previous
//
#include <hip/hip_runtime.h>
#include <hip/hip_bf16.h>
#include <cstdint>

// Problem constants
#define LL 3
#define NN 512
#define DD 1024
#define HH 4096
#define SS 24576    // B*N*L tokens
#define LNTOK 1536  // L*N tokens per batch
#define CAP 8192    // ceil(S/E)

// ws offsets in 4-byte words (total 115968 words = 464 KB; round-1 proved >=565 KB available)
#define OFF_IDX   0        // int[S]
#define OFF_GVAL  24576    // float[S]
#define OFF_HIST  49152    // int[96*3] (pad 512)
#define OFF_CBASE 49664    // int[96*3] (pad 512)
#define OFF_GSUM  50176    // float[3] (pad 64)
#define OFF_GBE   50240    // float[16*3] (pad 64)
#define OFF_CNTI  50304    // int[16]
#define OFF_CNTB  50320    // float[16] (pad to 50432)
#define OFF_Z     50432    // float[16*3*1024]
#define OFF_YS    99584    // float[16*1024]
#define OFF_END   115968

// ---------------------------------------------------------------------------
// K0: mask zero-count per batch. grid 96 x 256 (256 mask elems per block).
__global__ __launch_bounds__(256) void k0_mask(const void* __restrict__ maskp,
                                               int* __restrict__ cnti) {
  __shared__ int det;
  __shared__ int scnt;
  int tid = threadIdx.x;
  if (tid == 0) { det = 0; scnt = 0; }
  __syncthreads();
  const uint32_t* mw = (const uint32_t*)maskp;
  // sniff encoding over first LNTOK words (L2-cached; benign same-value race)
  for (int i = tid; i < LNTOK; i += 256) {
    uint32_t v = mw[i];
    if (v == 0x3F800000u) det = 2;        // float32 0/1
    else if (v > 1u) det = 1;             // packed bool bytes
  }
  __syncthreads();
  int mode = det;
  int t = blockIdx.x * 256 + tid;
  int zero;
  if (mode == 1) zero = (((const uint8_t*)maskp)[t] == 0);
  else           zero = (mw[t] == 0);
  unsigned long long bal = __ballot(zero);
  if ((tid & 63) == 0) atomicAdd(&scnt, __popcll(bal));
  __syncthreads();
  if (tid == 0) atomicAdd(&cnti[blockIdx.x / 6], scnt);  // 6 blocks per batch
}

// ---------------------------------------------------------------------------
// K1: fused gating + unconditional z accumulation (single x read).
// grid 384 x 256. Block = 64 tokens (same b). Wave = 16 tokens.
__global__ __launch_bounds__(256) void k1_fused(const float* __restrict__ x,
                                                const float* __restrict__ wg,
                                                int* __restrict__ idx,
                                                float* __restrict__ gval,
                                                int* __restrict__ hist,
                                                float* __restrict__ gsum,
                                                float* __restrict__ gbe,
                                                float* __restrict__ z) {
  __shared__ float wgT[3][1024];
  __shared__ float zp[3][1024];
  __shared__ float sG[3];
  int tid = threadIdx.x;
  for (int i = tid; i < 3072; i += 256) {
    wgT[i % 3][i / 3] = wg[i];
    ((float*)zp)[i] = 0.f;
  }
  if (tid < 3) sG[tid] = 0.f;
  __syncthreads();
  int lane = tid & 63, w = tid >> 6;
  int t0 = blockIdx.x * 64;
  int b = t0 / LNTOK;                 // 1536 % 64 == 0 -> uniform per block
  float a0[16], a1[16], a2[16];
#pragma unroll
  for (int j = 0; j < 16; ++j) { a0[j] = 0.f; a1[j] = 0.f; a2[j] = 0.f; }
  float lg0 = 0, lg1 = 0, lg2 = 0, lb0 = 0, lb1 = 0, lb2 = 0;
  int lh0 = 0, lh1 = 0, lh2 = 0;
  int tbase = t0 + w * 16;
  for (int k = 0; k < 16; ++k) {
    int t = tbase + k;
    int r = t % LNTOK;
    int n = r / LL, l = r % LL;
    const float* row = x + (size_t)((b * LL + l) * NN + n) * DD;
    float4 xv[4];
#pragma unroll
    for (int q = 0; q < 4; ++q)
      xv[q] = *(const float4*)(row + q * 256 + lane * 4);
    float d0 = 0, d1 = 0, d2 = 0;
#pragma unroll
    for (int q = 0; q < 4; ++q) {
      int dd = q * 256 + lane * 4;
      float4 w0 = *(const float4*)(&wgT[0][dd]);
      float4 w1 = *(const float4*)(&wgT[1][dd]);
      float4 w2 = *(const float4*)(&wgT[2][dd]);
      d0 += xv[q].x * w0.x + xv[q].y * w0.y + xv[q].z * w0.z + xv[q].w * w0.w;
      d1 += xv[q].x * w1.x + xv[q].y * w1.y + xv[q].z * w1.z + xv[q].w * w1.w;
      d2 += xv[q].x * w2.x + xv[q].y * w2.y + xv[q].z * w2.z + xv[q].w * w2.w;
    }
#pragma unroll
    for (int off = 32; off; off >>= 1) {
      d0 += __shfl_xor(d0, off);
      d1 += __shfl_xor(d1, off);
      d2 += __shfl_xor(d2, off);
    }
    float m = d0; int id = 0;
    if (d1 > m) { m = d1; id = 1; }
    if (d2 > m) { m = d2; id = 2; }
    float e0 = expf(d0 - m), e1 = expf(d1 - m), e2 = expf(d2 - m);
    float inv = 1.0f / (e0 + e1 + e2);   // softmax prob of argmax expert
    if (lane == 0) {
      idx[t] = id;
      gval[t] = inv;
      lg0 += e0 * inv; lg1 += e1 * inv; lg2 += e2 * inv;
      if (id == 0) { lh0++; lb0 += inv; }
      else if (id == 1) { lh1++; lb1 += inv; }
      else { lh2++; lb2 += inv; }
    }
    if (id == 0) {
#pragma unroll
      for (int q = 0; q < 4; ++q) {
        a0[q * 4 + 0] += inv * xv[q].x; a0[q * 4 + 1] += inv * xv[q].y;
        a0[q * 4 + 2] += inv * xv[q].z; a0[q * 4 + 3] += inv * xv[q].w;
      }
    } else if (id == 1) {
#pragma unroll
      for (int q = 0; q < 4; ++q) {
        a1[q * 4 + 0] += inv * xv[q].x; a1[q * 4 + 1] += inv * xv[q].y;
        a1[q * 4 + 2] += inv * xv[q].z; a1[q * 4 + 3] += inv * xv[q].w;
      }
    } else {
#pragma unroll
      for (int q = 0; q < 4; ++q) {
        a2[q * 4 + 0] += inv * xv[q].x; a2[q * 4 + 1] += inv * xv[q].y;
        a2[q * 4 + 2] += inv * xv[q].z; a2[q * 4 + 3] += inv * xv[q].w;
      }
    }
  }
  if (lane == 0) {
    atomicAdd(&sG[0], lg0); atomicAdd(&sG[1], lg1); atomicAdd(&sG[2], lg2);
    atomicAdd(&gbe[b * 3 + 0], lb0);
    atomicAdd(&gbe[b * 3 + 1], lb1);
    atomicAdd(&gbe[b * 3 + 2], lb2);
    int chunk = blockIdx.x >> 2;
    atomicAdd(&hist[chunk * 3 + 0], lh0);
    atomicAdd(&hist[chunk * 3 + 1], lh1);
    atomicAdd(&hist[chunk * 3 + 2], lh2);
  }
  // z: register -> LDS atomic partial -> global atomic
#pragma unroll
  for (int q = 0; q < 4; ++q) {
    int dd = q * 256 + lane * 4;
#pragma unroll
    for (int j = 0; j < 4; ++j) {
      atomicAdd(&zp[0][dd + j], a0[q * 4 + j]);
      atomicAdd(&zp[1][dd + j], a1[q * 4 + j]);
      atomicAdd(&zp[2][dd + j], a2[q * 4 + j]);
    }
  }
  __syncthreads();
  if (tid < 3) atomicAdd(&gsum[tid], sG[tid]);
  for (int i = tid; i < 3072; i += 256)
    atomicAdd(&z[(size_t)b * 3072 + i], ((float*)zp)[i]);
}

// ---------------------------------------------------------------------------
// K2: chunk prefix scan + l_aux + cnt->float. 1 block x 64.
__global__ void k2_scan(const int* __restrict__ hist, int* __restrict__ cbase,
                        const float* __restrict__ gsum,
                        const int* __restrict__ cnti, float* __restrict__ cntb,
                        float* __restrict__ out_laux) {
  int tid = threadIdx.x;
  if (tid < 16) { int c = cnti[tid]; cntb[tid] = (float)(c < 1 ? 1 : c); }
  if (tid == 0) {
    int r0 = 0, r1 = 0, r2 = 0;
    for (int c = 0; c < 96; ++c) {
      cbase[c * 3 + 0] = r0; cbase[c * 3 + 1] = r1; cbase[c * 3 + 2] = r2;
      r0 += hist[c * 3 + 0]; r1 += hist[c * 3 + 1]; r2 += hist[c * 3 + 2];
    }
    float invS = 1.0f / (float)SS;
    *out_laux = 3.0f * (gsum[0] * invS * ((float)r0 * invS) +
                        gsum[1] * invS * ((float)r1 * invS) +
                        gsum[2] * invS * ((float)r2 * invS));
  }
}

// ---------------------------------------------------------------------------
// K3: dropped-token correction: z -= g*x, gbe -= g for pos >= CAP.
// grid 96 x 256 (one 256-token chunk per block).
__global__ __launch_bounds__(256) void k3_corr(const float* __restrict__ x,
                                               const int* __restrict__ idx,
                                               const float* __restrict__ gval,
                                               const int* __restrict__ cbase,
                                               float* __restrict__ gbe,
                                               float* __restrict__ z) {
  __shared__ int whist[4][3];
  int tid = threadIdx.x;
  int t = blockIdx.x * 256 + tid;
  int e = idx[t];
  float gv = gval[t];
  int lane = tid & 63, w = tid >> 6;
  unsigned long long m0 = __ballot(e == 0);
  unsigned long long m1 = __ballot(e == 1);
  unsigned long long m2 = __ballot(e == 2);
  if (lane == 0) {
    whist[w][0] = __popcll(m0);
    whist[w][1] = __popcll(m1);
    whist[w][2] = __popcll(m2);
  }
  __syncthreads();
  int pre = 0;
  for (int ww = 0; ww < 3; ++ww)
    if (ww < w) pre += whist[ww][e];
  unsigned long long lt = (1ull << lane) - 1ull;
  unsigned long long me = (e == 0) ? m0 : (e == 1) ? m1 : m2;
  int pos = cbase[blockIdx.x * 3 + e] + pre + __popcll(me & lt);
  bool drop = (pos >= CAP);
  unsigned long long db = __ballot(drop);
  int b = t / LNTOK;  // 256 | 1536 -> uniform per block
  while (db) {
    int l = __ffsll((long long)db) - 1;
    db &= db - 1;
    int te = __shfl(e, l);
    float tg = __shfl(gv, l);
    int t2 = blockIdx.x * 256 + w * 64 + l;
    int r = t2 % LNTOK;
    int n = r / LL, ll = r % LL;
    const float* row = x + (size_t)((b * LL + ll) * NN + n) * DD;
    float* zr = z + (size_t)b * 3072 + te * 1024;
#pragma unroll
    for (int q = 0; q < 4; ++q) {
      int dd = q * 256 + lane * 4;
      float4 v = *(const float4*)(row + dd);
      atomicAdd(&zr[dd + 0], -tg * v.x);
      atomicAdd(&zr[dd + 1], -tg * v.y);
      atomicAdd(&zr[dd + 2], -tg * v.z);
      atomicAdd(&zr[dd + 3], -tg * v.w);
    }
    if (lane == 0) atomicAdd(&gbe[b * 3 + te], -tg);
  }
}

// ---------------------------------------------------------------------------
// K4a: ys init with bias: ys[b,d] = sum_e gbe[b,e]*be[e,d]. grid 64 x 256.
__global__ __launch_bounds__(256) void k4a_init(const float* __restrict__ gbe,
                                                const float* __restrict__ be,
                                                float* __restrict__ ys) {
  int i = blockIdx.x * 256 + threadIdx.x;  // 16384
  int bb = i >> 10, d = i & 1023;
  ys[i] = gbe[bb * 3 + 0] * be[0 * DD + d] +
          gbe[bb * 3 + 1] * be[1 * DD + d] +
          gbe[bb * 3 + 2] * be[2 * DD + d];
}

// ---------------------------------------------------------------------------
// K4: ys += z[16,3072] @ We[3072,1024]. grid 384 = 16 n-tiles(64) x 24 k-chunks(128).
__global__ __launch_bounds__(256) void k4_we(const float* __restrict__ z,
                                             const float* __restrict__ We,
                                             float* __restrict__ ys) {
  __shared__ float zt[16][128];
  __shared__ float Ct[16][64];
  int tid = threadIdx.x;
  int nt = blockIdx.x & 15, ks = blockIdx.x >> 4;
  int n0 = nt * 64, k0 = ks * 128;
  for (int i = tid; i < 2048; i += 256) {
    int m = i >> 7, kk = i & 127;
    zt[m][kk] = z[m * 3072 + k0 + kk];
  }
  for (int i = tid; i < 1024; i += 256) ((float*)Ct)[i] = 0.f;
  __syncthreads();
  int nl = tid & 63, kg = tid >> 6;  // 4 k-groups of 32
  float acc[16];
#pragma unroll
  for (int m = 0; m < 16; ++m) acc[m] = 0.f;
  for (int kk = kg * 32; kk < kg * 32 + 32; ++kk) {
    float bv = We[(size_t)(k0 + kk) * 1024 + n0 + nl];
#pragma unroll
    for (int m = 0; m < 16; ++m) acc[m] += zt[m][kk] * bv;
  }
#pragma unroll
  for (int m = 0; m < 16; ++m) atomicAdd(&Ct[m][nl], acc[m]);
  __syncthreads();
  for (int i = tid; i < 1024; i += 256) {
    int m = i >> 6, h = i & 63;
    atomicAdd(&ys[m * 1024 + n0 + h], Ct[m][h]);
  }
}

// ---------------------------------------------------------------------------
// K5a: out init: out[b,h] = 1536*bp[h]/cnt[b]. grid 256 x 256.
__global__ __launch_bounds__(256) void k5a_init(const float* __restrict__ bp,
                                                const float* __restrict__ cntb,
                                                float* __restrict__ out) {
  int i = blockIdx.x * 256 + threadIdx.x;  // 65536
  int bb = i >> 12, h = i & 4095;
  out[i] = (float)LNTOK * bp[h] / cntb[bb];
}

// ---------------------------------------------------------------------------
// K5: out += (ys[16,1024] @ Wp[1024,4096]) / cnt. grid 512 = 64 h-tiles(64) x 8 k-chunks(128).
__global__ __launch_bounds__(256) void k5_out(const float* __restrict__ ys,
                                              const float* __restrict__ Wp,
                                              const float* __restrict__ cntb,
                                              float* __restrict__ out) {
  __shared__ float yt[16][128];
  __shared__ float Ct[16][64];
  __shared__ float sinv[16];
  int tid = threadIdx.x;
  int ht = blockIdx.x & 63, ks = blockIdx.x >> 6;
  int n0 = ht * 64, k0 = ks * 128;
  for (int i = tid; i < 2048; i += 256) {
    int m = i >> 7, kk = i & 127;
    yt[m][kk] = ys[m * 1024 + k0 + kk];
  }
  for (int i = tid; i < 1024; i += 256) ((float*)Ct)[i] = 0.f;
  if (tid < 16) sinv[tid] = 1.0f / cntb[tid];
  __syncthreads();
  int nl = tid & 63, kg = tid >> 6;  // 4 k-groups of 32
  float acc[16];
#pragma unroll
  for (int m = 0; m < 16; ++m) acc[m] = 0.f;
  for (int kk = kg * 32; kk < kg * 32 + 32; ++kk) {
    float bv = Wp[(size_t)(k0 + kk) * HH + n0 + nl];
#pragma unroll
    for (int m = 0; m < 16; ++m) acc[m] += yt[m][kk] * bv;
  }
#pragma unroll
  for (int m = 0; m < 16; ++m) atomicAdd(&Ct[m][nl], acc[m]);
  __syncthreads();
  for (int i = tid; i < 1024; i += 256) {
    int m = i >> 6, h = i & 63;
    atomicAdd(&out[(size_t)m * HH + n0 + h], Ct[m][h] * sinv[m]);
  }
}

// ---------------------------------------------------------------------------
extern "C" void kernel_launch(void* const* d_in, const int* in_sizes, int n_in,
                              void* d_out, int out_size, void* d_ws, size_t ws_size,
                              hipStream_t stream) {
  const float* x    = (const float*)d_in[0];
  const void*  mask = d_in[1];
  const float* wg   = (const float*)d_in[2];
  const float* We   = (const float*)d_in[3];
  const float* be   = (const float*)d_in[4];
  const float* Wp   = (const float*)d_in[5];
  const float* bp   = (const float*)d_in[6];
  float* out = (float*)d_out;
  float* wsf = (float*)d_ws;
  int*   wsi = (int*)d_ws;

  // zero all atomic targets every call (ws is not re-poisoned between replays)
  hipMemsetAsync((char*)d_ws + (size_t)OFF_HIST * 4, 0,
                 (size_t)(OFF_YS - OFF_HIST) * 4, stream);

  k0_mask<<<96, 256, 0, stream>>>(mask, wsi + OFF_CNTI);
  k1_fused<<<384, 256, 0, stream>>>(x, wg, wsi + OFF_IDX, wsf + OFF_GVAL,
                                    wsi + OFF_HIST, wsf + OFF_GSUM,
                                    wsf + OFF_GBE, wsf + OFF_Z);
  k2_scan<<<1, 64, 0, stream>>>(wsi + OFF_HIST, wsi + OFF_CBASE,
                                wsf + OFF_GSUM, wsi + OFF_CNTI,
                                wsf + OFF_CNTB, out + 65536);
  k3_corr<<<96, 256, 0, stream>>>(x, wsi + OFF_IDX, wsf + OFF_GVAL,
                                  wsi + OFF_CBASE, wsf + OFF_GBE, wsf + OFF_Z);
  k4a_init<<<64, 256, 0, stream>>>(wsf + OFF_GBE, be, wsf + OFF_YS);
  k4_we<<<384, 256, 0, stream>>>(wsf + OFF_Z, We, wsf + OFF_YS);
  k5a_init<<<256, 256, 0, stream>>>(bp, wsf + OFF_CNTB, out);
  k5_out<<<512, 256, 0, stream>>>(wsf + OFF_YS, Wp, wsf + OFF_CNTB, out);
}